// Round 16
// baseline (567.248 us; speedup 1.0000x reference)
//
#include <hip/hip_runtime.h>
#include <hip/hip_bf16.h>
#include <math.h>

// Sizes
#define NB 2
#define NL 4096
#define ND 1024
#define NH 4
#define NDK 256
#define NDV 256
#define NCH 128          // chunks per (b,h)
#define NBL (NB*NL)      // 8192

typedef __attribute__((ext_vector_type(8))) short short8;
typedef __attribute__((ext_vector_type(4))) short short4v;
typedef __attribute__((ext_vector_type(4))) float float4v;

#define MFMA16(a,b,c) __builtin_amdgcn_mfma_f32_16x16x32_bf16(a,b,c,0,0,0)

__device__ __forceinline__ short f2bs(float f){
  union { __hip_bfloat16 h; short s; } u; u.h = __float2bfloat16(f); return u.s;
}
__device__ __forceinline__ float bs2f(short s){
  union { float f; unsigned u; } u; u.u = ((unsigned)(unsigned short)s) << 16; return u.f;
}
__device__ __forceinline__ void store_c(float* p, float v){ *p = v; }
__device__ __forceinline__ void store_c(short* p, float v){ *p = f2bs(v); }

__device__ __forceinline__ void gload16(const short* g, short* l){
  __builtin_amdgcn_global_load_lds(
      (const __attribute__((address_space(1))) unsigned int*)g,
      (__attribute__((address_space(3))) unsigned int*)l, 16, 0, 0);
}
__device__ __forceinline__ void lds_barrier(){
  asm volatile("s_waitcnt lgkmcnt(0)" ::: "memory");
  __builtin_amdgcn_s_barrier();
  asm volatile("" ::: "memory");
}

// ---------------- casts (vectorized, G13) ----------------
__global__ void k_cast8(const float* __restrict__ s, short* __restrict__ d, int n8){
  int i = blockIdx.x*256 + threadIdx.x;
  if(i >= n8) return;
  const float4v a = *(const float4v*)(s + (size_t)i*8);
  const float4v b = *(const float4v*)(s + (size_t)i*8 + 4);
  short8 o;
  #pragma unroll
  for(int j=0;j<4;j++){ o[j] = f2bs(a[j]); o[4+j] = f2bs(b[j]); }
  *(short8*)(d + (size_t)i*8) = o;
}
// merged weight cast: y=0..2 -> qw/kw/vw -> wmega; y=3 -> w1 cols 0..1023 -> wmega;
// y=4 -> ow -> owbf
__global__ void k_castW(const float* __restrict__ qw, const float* __restrict__ kw,
                        const float* __restrict__ vw, const float* __restrict__ w1,
                        const float* __restrict__ ow, short* __restrict__ wmega,
                        short* __restrict__ owbf){
  const int which = blockIdx.y;
  const int i = blockIdx.x*256 + threadIdx.x;   // 131072 groups of 8
  short* d;
  const float* sp;
  size_t doff;
  if(which < 3){
    const float* s = which==0 ? qw : which==1 ? kw : vw;
    d = wmega + (size_t)which*1024*1024;
    sp = s + (size_t)i*8;
    doff = (size_t)i*8;
  } else if(which == 3){
    int r = i >> 7, c0 = (i & 127)*8;
    d = wmega + (size_t)3*1024*1024;
    sp = w1 + (size_t)r*1040 + c0;
    doff = (size_t)r*1024 + c0;
  } else {
    d = owbf;
    sp = ow + (size_t)i*8;
    doff = (size_t)i*8;
  }
  const float4v a = *(const float4v*)sp;
  const float4v b = *(const float4v*)(sp + 4);
  short8 o;
  #pragma unroll
  for(int j=0;j<4;j++){ o[j] = f2bs(a[j]); o[4+j] = f2bs(b[j]); }
  *(short8*)(d + doff) = o;
}

// ---------------- fused QKVG GEMM: C(8192x4096) = A*Wmega^T, 4-way output ----
__launch_bounds__(256)
__global__ void k_gemm4(const short* __restrict__ A, const short* __restrict__ Bt,
                        short* __restrict__ oq, short* __restrict__ ok,
                        short* __restrict__ ov, short* __restrict__ og){
  const int K = 1024;
  __shared__ short As[128*32];
  __shared__ short Bs[128*32];
  const int tid = threadIdx.x;
  const int w = tid >> 6, lane = tid & 63, lr = lane & 15, lg = lane >> 4;
  const int bm = blockIdx.x*128 + (w >> 1)*64;
  const int bnl = (blockIdx.y & 7)*128 + (w & 1)*64;   // col within 1024-wide output
  short* C = (blockIdx.y>>3)==0 ? oq : (blockIdx.y>>3)==1 ? ok
           : (blockIdx.y>>3)==2 ? ov : og;
  float4v acc[4][4];
  #pragma unroll
  for(int i=0;i<4;i++)
    #pragma unroll
    for(int j=0;j<4;j++) acc[i][j] = (float4v){0.f,0.f,0.f,0.f};
  const short* ga0 = A  + (size_t)(blockIdx.x*128 + (tid>>2))*K + (tid&3)*8;
  const short* ga1 = ga0 + (size_t)64*K;
  const short* gb0 = Bt + (size_t)(blockIdx.y*128 + (tid>>2))*K + (tid&3)*8;
  const short* gb1 = gb0 + (size_t)64*K;
  short* la0 = As + w*512;
  short* la1 = As + 2048 + w*512;
  short* lb0 = Bs + w*512;
  short* lb1 = Bs + 2048 + w*512;
  const int arow = (w>>1)*64, brow = (w&1)*64;
  for(int kk=0; kk<K; kk+=32){
    gload16(ga0+kk, la0);
    gload16(ga1+kk, la1);
    gload16(gb0+kk, lb0);
    gload16(gb1+kk, lb1);
    __syncthreads();
    short8 a[4], b[4];
    #pragma unroll
    for(int i=0;i<4;i++) a[i] = *(const short8*)(As + (arow + i*16 + lr)*32 + lg*8);
    #pragma unroll
    for(int j=0;j<4;j++) b[j] = *(const short8*)(Bs + (brow + j*16 + lr)*32 + lg*8);
    #pragma unroll
    for(int i=0;i<4;i++)
      #pragma unroll
      for(int j=0;j<4;j++)
        acc[i][j] = MFMA16(a[i], b[j], acc[i][j]);
    __syncthreads();
  }
  #pragma unroll
  for(int i=0;i<4;i++){
    int row0 = bm + i*16 + lg*4;
    #pragma unroll
    for(int j=0;j<4;j++){
      short* cp = C + (size_t)row0*1024 + bnl + j*16 + lr;
      #pragma unroll
      for(int r=0;r<4;r++) cp[(size_t)r*1024] = f2bs(acc[i][j][r]);
    }
  }
}

// ---------------- GEMM: C(MxN) = A(MxK)*Bt(NxK)^T, m97 structure ------------
template<typename OT>
__launch_bounds__(256)
__global__ void k_gemm(const short* __restrict__ A, const short* __restrict__ Bt,
                       OT* __restrict__ C, int M, int N, int K){
  __shared__ short As[128*32];
  __shared__ short Bs[128*32];
  const int tid = threadIdx.x;
  const int w = tid >> 6, lane = tid & 63, lr = lane & 15, lg = lane >> 4;
  const int bm = blockIdx.x*128 + (w >> 1)*64;
  const int bn = blockIdx.y*128 + (w & 1)*64;
  float4v acc[4][4];
  #pragma unroll
  for(int i=0;i<4;i++)
    #pragma unroll
    for(int j=0;j<4;j++) acc[i][j] = (float4v){0.f,0.f,0.f,0.f};
  const short* ga0 = A  + (size_t)(blockIdx.x*128 + (tid>>2))*K + (tid&3)*8;
  const short* ga1 = ga0 + (size_t)64*K;
  const short* gb0 = Bt + (size_t)(blockIdx.y*128 + (tid>>2))*K + (tid&3)*8;
  const short* gb1 = gb0 + (size_t)64*K;
  short* la0 = As + w*512;
  short* la1 = As + 2048 + w*512;
  short* lb0 = Bs + w*512;
  short* lb1 = Bs + 2048 + w*512;
  const int arow = (w>>1)*64, brow = (w&1)*64;
  for(int kk=0; kk<K; kk+=32){
    gload16(ga0+kk, la0);
    gload16(ga1+kk, la1);
    gload16(gb0+kk, lb0);
    gload16(gb1+kk, lb1);
    __syncthreads();
    short8 a[4], b[4];
    #pragma unroll
    for(int i=0;i<4;i++) a[i] = *(const short8*)(As + (arow + i*16 + lr)*32 + lg*8);
    #pragma unroll
    for(int j=0;j<4;j++) b[j] = *(const short8*)(Bs + (brow + j*16 + lr)*32 + lg*8);
    #pragma unroll
    for(int i=0;i<4;i++)
      #pragma unroll
      for(int j=0;j<4;j++)
        acc[i][j] = MFMA16(a[i], b[j], acc[i][j]);
    __syncthreads();
  }
  #pragma unroll
  for(int i=0;i<4;i++){
    int row0 = bm + i*16 + lg*4;
    #pragma unroll
    for(int j=0;j<4;j++){
      OT* cp = C + (size_t)row0*N + bn + j*16 + lr;
      #pragma unroll
      for(int r=0;r<4;r++) store_c(cp + (size_t)r*N, acc[i][j][r]);
    }
  }
}

// ---------------- depthwise causal conv K=4 + SiLU (merged 3-in-1) ----------
__global__ void k_conv_silu3(const short* __restrict__ qp, const short* __restrict__ kp,
                             const short* __restrict__ vp, const float* __restrict__ qcw,
                             const float* __restrict__ kcw, const float* __restrict__ vcw,
                             short* __restrict__ qc, short* __restrict__ kc,
                             short* __restrict__ vc){
  const int which = blockIdx.y;
  const short* x = which==0 ? qp : which==1 ? kp : vp;
  const float* wgt = which==0 ? qcw : which==1 ? kcw : vcw;
  short* y = which==0 ? qc : which==1 ? kc : vc;
  int i8 = blockIdx.x*256 + threadIdx.x;
  int c0 = (i8 & 127)*8;
  int l = (i8 >> 7) & (NL-1);
  size_t base = (size_t)i8*8;
  short8 xv[4];
  #pragma unroll
  for(int t=0;t<4;t++)
    xv[t] = (l >= t) ? *(const short8*)(x + base - (size_t)t*1024)
                     : (short8){0,0,0,0,0,0,0,0};
  short8 o;
  #pragma unroll
  for(int j=0;j<8;j++){
    const float4v w4 = *(const float4v*)(wgt + (c0+j)*4);
    float acc = 0.f;
    #pragma unroll
    for(int t=0;t<4;t++) if(l >= t) acc += bs2f(xv[t][j]) * w4[3-t];
    o[j] = f2bs(acc / (1.f + __expf(-acc)));
  }
  *(short8*)(y + base) = o;
}

// ---------------- beta = max(sigmoid(hs @ bw^T), 1e-6) ----------------
__global__ void k_beta(const float* __restrict__ hs, const float* __restrict__ bw,
                       float* __restrict__ beta){
  int w = threadIdx.x >> 6, lane = threadIdx.x & 63;
  int bl = blockIdx.x*4 + w;
  const float* x = hs + (size_t)bl*1024;
  float a[4] = {0.f,0.f,0.f,0.f};
  for(int d=lane; d<1024; d+=64){
    float xv = x[d];
    #pragma unroll
    for(int hh=0;hh<4;hh++) a[hh] += xv * bw[hh*1024 + d];
  }
  #pragma unroll
  for(int off=32; off; off>>=1)
    #pragma unroll
    for(int hh=0;hh<4;hh++) a[hh] += __shfl_down(a[hh], off);
  if(lane == 0)
    #pragma unroll
    for(int hh=0;hh<4;hh++)
      beta[(size_t)bl*4 + hh] = fmaxf(1.f/(1.f+__expf(-a[hh])), 1e-6f);
}

// ---------------- delta phase A: per-chunk prep (reg substitution) ----------
#define PADA 260
__launch_bounds__(256)
__global__ void k_phaseA(const short* __restrict__ q, const short* __restrict__ k,
                         const short* __restrict__ v, const float* __restrict__ beta,
                         short* __restrict__ qn_o, short* __restrict__ wn_o,
                         short* __restrict__ kT_o, short* __restrict__ at_o,
                         float* __restrict__ u_o){
  __shared__ float qn[32*PADA];
  __shared__ float kn[32*PADA];
  __shared__ float vb[32*PADA];
  __shared__ float kb[32*PADA];
  __shared__ float Ml[32*33];
  __shared__ float bet[32];
  const int tid = threadIdx.x;
  const int n = blockIdx.x % NCH;
  const int h = (blockIdx.x / NCH) % NH;
  const int b = blockIdx.x / (NCH*NH);
  size_t rowbase = ((size_t)b*NL + n*32)*1024 + h*256;
  if(tid < 32) bet[tid] = beta[((size_t)b*NL + n*32 + tid)*4 + h];
  for(int r=0;r<32;r++){
    qn[r*PADA + tid] = bs2f(q[rowbase + (size_t)r*1024 + tid]);
    kn[r*PADA + tid] = bs2f(k[rowbase + (size_t)r*1024 + tid]);
    vb[r*PADA + tid] = bs2f(v[rowbase + (size_t)r*1024 + tid]);
  }
  __syncthreads();
  { // l2norm q,k rows; kb = kn*beta; vb *= beta
    int row = tid >> 3, sub = tid & 7;
    float sq = 0.f, sk = 0.f;
    for(int kk=0; kk<32; kk++){
      int d = sub + 8*kk;
      float a0 = qn[row*PADA+d]; sq += a0*a0;
      float a1 = kn[row*PADA+d]; sk += a1*a1;
    }
    #pragma unroll
    for(int off=1; off<8; off<<=1){ sq += __shfl_xor(sq, off); sk += __shfl_xor(sk, off); }
    float rq = rsqrtf(sq + 1e-6f), rk = rsqrtf(sk + 1e-6f);
    float be = bet[row];
    for(int kk=0; kk<32; kk++){
      int d = sub + 8*kk;
      qn[row*PADA+d] *= rq;
      float kv = kn[row*PADA+d]*rk;
      kn[row*PADA+d] = kv;
      kb[row*PADA+d] = kv*be;
      vb[row*PADA+d] *= be;
    }
  }
  __syncthreads();
  { // MFMA: w0-1: M = kb@kn^T (strict lower) -> Ml; w2-3: attn = tril(qn@kn^T)
    int w = tid >> 6, lane = tid & 63, lr = lane & 15, lg = lane >> 4;
    int m0 = (w & 1)*16;
    const float* Asrc = (w < 2) ? kb : qn;
    float4v acc0 = (float4v){0.f,0.f,0.f,0.f}, acc1 = (float4v){0.f,0.f,0.f,0.f};
    for(int kc=0; kc<8; kc++){
      int kof = kc*32 + lg*8;
      short8 af, b0, b1;
      const float* ap  = Asrc + (m0+lr)*PADA + kof;
      const float* bp0 = kn + lr*PADA + kof;
      const float* bp1 = kn + (16+lr)*PADA + kof;
      #pragma unroll
      for(int j=0;j<8;j++){ af[j]=f2bs(ap[j]); b0[j]=f2bs(bp0[j]); b1[j]=f2bs(bp1[j]); }
      acc0 = MFMA16(af, b0, acc0);
      acc1 = MFMA16(af, b1, acc1);
    }
    if(w < 2){
      #pragma unroll
      for(int r=0;r<4;r++){
        int row = m0 + lg*4 + r;
        Ml[row*33 + lr]      = (lr      < row) ? acc0[r] : 0.f;
        Ml[row*33 + 16 + lr] = ((16+lr) < row) ? acc1[r] : 0.f;
      }
    } else {
      size_t abase = (size_t)blockIdx.x * 1024;
      #pragma unroll
      for(int r=0;r<4;r++){
        int row = m0 + lg*4 + r;
        at_o[abase + row*32 + lr]      = (lr      <= row) ? f2bs(acc0[r]) : (short)0;
        at_o[abase + row*32 + 16 + lr] = ((16+lr) <= row) ? f2bs(acc1[r]) : (short)0;
      }
    }
  }
  __syncthreads();
  // forward substitution in REGISTERS: thread tid owns column d=tid of vb,kb.
  float vbr[32], kbr[32];
  #pragma unroll
  for(int t=0;t<32;t++){
    vbr[t] = vb[t*PADA + tid];
    kbr[t] = kb[t*PADA + tid];
  }
  #pragma unroll
  for(int i=1;i<32;i++){
    float su = 0.f, sw = 0.f;
    const float* Mr = Ml + i*33;
    #pragma unroll
    for(int t=0;t<i;t++){
      float m = Mr[t];
      su += m * vbr[t];
      sw += m * kbr[t];
    }
    vbr[i] -= su;
    kbr[i] -= sw;
  }
  { // stores: wn/u straight from registers; qn/kT from LDS
    size_t obase = (size_t)blockIdx.x * 8192;
    #pragma unroll
    for(int it=0; it<32; it++){
      int idx = it*256 + tid;
      qn_o[obase + idx] = f2bs(qn[it*PADA + tid]);
      wn_o[obase + idx] = f2bs(-kbr[it]);
      u_o [obase + idx] = vbr[it];
      int tt = idx & 31, dd = idx >> 5;
      kT_o[obase + idx] = f2bs(kn[tt*PADA + dd]);
    }
  }
}

// ---------------- delta phase B: R8 4-wave structure (proven 182us) ----------
struct FragsB {
  short8 a[8];     // wn (w<2) or qn (w>=2) fragments
  short8 kt[4];    // kT fragments
  short8 at;       // attn fragment (w>=2 only)
  float4v u;       // u slice (w<2 only)
};

__device__ __forceinline__ void loadFrags(FragsB& f, size_t cb,
    const short* __restrict__ qn, const short* __restrict__ wn,
    const short* __restrict__ kT, const short* __restrict__ at,
    const float* __restrict__ u, int w, int lr, int lg, int m0, int c0){
  const short* kT_b = kT + cb*8192;
  #pragma unroll
  for(int mi=0;mi<4;mi++)
    f.kt[mi] = *(const short8*)(kT_b + ((w*4+mi)*16 + lr)*32 + lg*8);
  if(w < 2){
    const short* wn_b = wn + cb*8192;
    #pragma unroll
    for(int kc=0;kc<8;kc++)
      f.a[kc] = *(const short8*)(wn_b + (m0+lr)*256 + kc*32 + lg*8);
    const float* up = u + cb*8192 + (size_t)(m0 + lg*4)*256 + c0 + lr;
    #pragma unroll
    for(int r=0;r<4;r++) f.u[r] = up[(size_t)r*256];
  } else {
    const short* qn_b = qn + cb*8192;
    #pragma unroll
    for(int kc=0;kc<8;kc++)
      f.a[kc] = *(const short8*)(qn_b + (m0+lr)*256 + kc*32 + lg*8);
    f.at = *(const short8*)(at + cb*1024 + (m0+lr)*32 + lg*8);
  }
}

__device__ __forceinline__ void computeChunk(const FragsB& f, int n,
    float4v (&Sreg)[4], float* __restrict__ ua, short* __restrict__ ScT,
    short* __restrict__ dout, int b, int h, int c0,
    int w, int lr, int lg, int m0, int swz){
  char* scb = (char*)ScT;
  lds_barrier();   // prev chunk's ScT writes visible
  float4v oacc = (float4v){0.f,0.f,0.f,0.f};
  if(w < 2){
    float4v acc = f.u, acc2 = (float4v){0.f,0.f,0.f,0.f};
    #pragma unroll
    for(int kc=0;kc<4;kc++){
      short8 s0 = *(const short8*)(scb + (((lr<<9) + ((kc*32 + lg*8)<<1)) ^ swz));
      short8 s1 = *(const short8*)(scb + (((lr<<9) + (((kc+4)*32 + lg*8)<<1)) ^ swz));
      acc  = MFMA16(f.a[kc],   s0, acc);
      acc2 = MFMA16(f.a[kc+4], s1, acc2);
    }
    #pragma unroll
    for(int r=0;r<4;r++) ua[(m0 + lg*4 + r)*18 + lr] = acc[r] + acc2[r];
  } else {
    float4v acc2 = (float4v){0.f,0.f,0.f,0.f};
    #pragma unroll
    for(int kc=0;kc<4;kc++){
      short8 s0 = *(const short8*)(scb + (((lr<<9) + ((kc*32 + lg*8)<<1)) ^ swz));
      short8 s1 = *(const short8*)(scb + (((lr<<9) + (((kc+4)*32 + lg*8)<<1)) ^ swz));
      oacc = MFMA16(f.a[kc],   s0, oacc);
      acc2 = MFMA16(f.a[kc+4], s1, acc2);
    }
    #pragma unroll
    for(int r=0;r<4;r++) oacc[r] += acc2[r];
  }
  lds_barrier();   // ua visible
  short8 bu;
  #pragma unroll
  for(int j=0;j<8;j++) bu[j] = f2bs(ua[(lg*8 + j)*18 + lr]);
  if(w >= 2){
    oacc = MFMA16(f.at, bu, oacc);
    short* ob = dout + ((size_t)b*NL + n*32 + m0 + lg*4)*1024 + h*256 + c0 + lr;
    #pragma unroll
    for(int r=0;r<4;r++) ob[(size_t)r*1024] = f2bs(oacc[r]);
  }
  #pragma unroll
  for(int mi=0; mi<4; mi++){
    Sreg[mi] = MFMA16(f.kt[mi], bu, Sreg[mi]);   // S += kT @ u_adj
    int rowb = (w*4 + mi)*16 + lg*4;
    short4v pk;
    #pragma unroll
    for(int r=0;r<4;r++) pk[r] = f2bs(Sreg[mi][r]);
    *(short4v*)(scb + (((lr<<9) + (rowb<<1)) ^ swz)) = pk;
  }
}

// grid 128: chain = bid&7 (all 16 blocks of a chain -> same XCD L2), cblk = bid>>3
__launch_bounds__(256, 1)
__global__ void k_phaseB(const short* __restrict__ qn, const short* __restrict__ wn,
                         const short* __restrict__ kT, const short* __restrict__ at,
                         const float* __restrict__ u, short* __restrict__ dout){
  __shared__ float ua[32*18];    // u_adj handoff
  __shared__ short ScT[4096];    // bf16 S shadow, col-major [c][row], XOR-swizzled
  const int tid = threadIdx.x;
  const int chain = blockIdx.x & 7;
  const int cblk = blockIdx.x >> 3;
  const int b = chain >> 2, h = chain & 3;
  const int c0 = cblk * 16;
  for(int i=tid; i<4096; i+=256) ScT[i] = 0;
  const int w = tid >> 6, lane = tid & 63, lr = lane & 15, lg = lane >> 4;
  const int m0 = (w & 1)*16;
  const size_t chunkbase = (size_t)(b*NH + h) * NCH;
  const int swz = (lr & 7) << 4;
  float4v Sreg[4];
  #pragma unroll
  for(int mi=0;mi<4;mi++) Sreg[mi] = (float4v){0.f,0.f,0.f,0.f};
  __syncthreads();
  FragsB fA, fB;
  loadFrags(fA, chunkbase, qn, wn, kT, at, u, w, lr, lg, m0, c0);
  for(int n=0; n<NCH; n+=2){
    loadFrags(fB, chunkbase + n+1, qn, wn, kT, at, u, w, lr, lg, m0, c0);
    computeChunk(fA, n, Sreg, ua, ScT, dout, b, h, c0, w, lr, lg, m0, swz);
    if(n+2 < NCH)
      loadFrags(fA, chunkbase + n+2, qn, wn, kT, at, u, w, lr, lg, m0, c0);
    computeChunk(fB, n+1, Sreg, ua, ScT, dout, b, h, c0, w, lr, lg, m0, swz);
  }
}

// ---------------- FIR convs (K=5 and K=64): register sliding window, no LDS --
__launch_bounds__(256, 2)
__global__ void k_fir(const short* __restrict__ v, const float* __restrict__ wS,
                      const float* __restrict__ wL, short* __restrict__ ls,
                      short* __restrict__ ll){
  const int tid = threadIdx.x;                 // d within head
  const int lt = blockIdx.x % (NL/32);
  const int h = (blockIdx.x / (NL/32)) % NH;
  const int b = blockIdx.x / ((NL/32)*NH);
  const int l0 = lt*32;
  const size_t colbase = (size_t)b*NL*1024 + h*256 + tid;
  const float* wLp = wL + (size_t)h*16384 + tid*64;
  const float* wSp = wS + (size_t)h*1280 + tid*5;
  float accL[32], accS[32];
  #pragma unroll
  for(int i=0;i<32;i++){ accL[i]=0.f; accS[i]=0.f; }
  { // chunk 0: taps j=0..31
    float w[32];
    #pragma unroll
    for(int j=0;j<32;j++) w[j] = wLp[j];
    float val[63];
    #pragma unroll
    for(int s=0;s<63;s++){
      int l = l0 - 63 + s;
      int lc = l < 0 ? 0 : l;
      float x = bs2f(v[colbase + (size_t)lc*1024]);
      val[s] = l < 0 ? 0.f : x;
    }
    #pragma unroll
    for(int i=0;i<32;i++)
      #pragma unroll
      for(int j=0;j<32;j++)
        accL[i] += val[i+j]*w[j];
  }
  { // chunk 1: taps j=32..63 (+ accS)
    float w[32];
    #pragma unroll
    for(int j=0;j<32;j++) w[j] = wLp[32+j];
    float w5[5];
    #pragma unroll
    for(int j=0;j<5;j++) w5[j] = wSp[j];
    float val[63];
    #pragma unroll
    for(int s=0;s<63;s++){
      int l = l0 - 31 + s;
      int lc = l < 0 ? 0 : l;
      float x = bs2f(v[colbase + (size_t)lc*1024]);
      val[s] = l < 0 ? 0.f : x;
    }
    #pragma unroll
    for(int i=0;i<32;i++){
      #pragma unroll
      for(int j=0;j<32;j++)
        accL[i] += val[i+j]*w[j];
      #pragma unroll
      for(int j=0;j<5;j++)
        accS[i] += val[i+27+j]*w5[j];  // v[l0-31+i+27+j] = v[l-4+j]
    }
  }
  #pragma unroll
  for(int i=0;i<32;i++){
    size_t ox = colbase + (size_t)(l0+i)*1024;
    ll[ox] = f2bs(accL[i]);
    ls[ox] = f2bs(accS[i]);
  }
}

// ---------------- fused gate + combine + rmsnorm (2-head passes) -------------
__launch_bounds__(256)
__global__ void k_gatecomb(const short* __restrict__ ls, const short* __restrict__ ll,
                           const short* __restrict__ dd, const short* __restrict__ vv,
                           const short* __restrict__ G, const float* __restrict__ w1,
                           const float* __restrict__ b1, const float* __restrict__ w2,
                           const float* __restrict__ b2, const float* __restrict__ ltp,
                           const float* __restrict__ crl, const float* __restrict__ nw,
                           short* __restrict__ obf){
  __shared__ float st[4][16];
  __shared__ float red[4][4][4];   // [wave][head][out]
  __shared__ float pl[4][4];
  __shared__ float rr2[4][4];
  const int tid = threadIdx.x;
  const size_t bl = blockIdx.x;
  {
    int row = tid >> 4, ln = tid & 15;
    int ten = row >> 2, hh = row & 3;
    const short* base = (ten==0 ? ls : ten==1 ? ll : ten==2 ? dd : vv) + (bl*4 + hh)*256;
    float s1=0.f, s2=0.f, sa=0.f;
    for(int kk=0; kk<16; kk++){
      float x = bs2f(base[ln + 16*kk]);
      s1 += x; s2 += x*x; sa += fabsf(x);
    }
    #pragma unroll
    for(int off=1; off<16; off<<=1){
      s1 += __shfl_xor(s1, off); s2 += __shfl_xor(s2, off); sa += __shfl_xor(sa, off);
    }
    if(ln == 0){
      float mean = s1 * (1.f/256.f);
      st[hh][ten*4+0] = mean;
      st[hh][ten*4+1] = s2*(1.f/256.f) - mean*mean;
      st[hh][ten*4+2] = sa*(1.f/256.f);
      st[hh][ten*4+3] = sqrtf(s2);
    }
  }
  __syncthreads();
  const int w = tid >> 6, lane = tid & 63;
  // two passes, 2 heads each: per-ii weight reads shared across the 2 heads
  #pragma unroll
  for(int p=0; p<2; p++){
    float s0r[16], s1r[16];
    #pragma unroll
    for(int s=0;s<16;s++){ s0r[s] = st[p*2][s]; s1r[s] = st[p*2+1][s]; }
    float lgA[4] = {0.f,0.f,0.f,0.f};
    float lgB[4] = {0.f,0.f,0.f,0.f};
    for(int ii=0; ii<4; ii++){
      int i = tid + ii*256;
      float g0 = bs2f(G[bl*1024 + i]) + b1[i];
      const float* wr = w1 + (size_t)i*1040 + 1024;
      float w2r[4];
      #pragma unroll
      for(int jj=0;jj<4;jj++) w2r[jj] = w2[jj*1024 + i];
      {
        float g = g0;
        #pragma unroll
        for(int s=0;s<16;s++) g += s0r[s]*wr[s];
        float z = 1.5957691216057308f*(g + 0.044715f*g*g*g);
        float hg = g / (1.f + __expf(-z));
        #pragma unroll
        for(int jj=0;jj<4;jj++) lgA[jj] += hg * w2r[jj];
      }
      {
        float g = g0;
        #pragma unroll
        for(int s=0;s<16;s++) g += s1r[s]*wr[s];
        float z = 1.5957691216057308f*(g + 0.044715f*g*g*g);
        float hg = g / (1.f + __expf(-z));
        #pragma unroll
        for(int jj=0;jj<4;jj++) lgB[jj] += hg * w2r[jj];
      }
    }
    #pragma unroll
    for(int off=32; off; off>>=1)
      #pragma unroll
      for(int jj=0;jj<4;jj++){
        lgA[jj] += __shfl_down(lgA[jj], off);
        lgB[jj] += __shfl_down(lgB[jj], off);
      }
    if(lane == 0)
      #pragma unroll
      for(int jj=0;jj<4;jj++){
        red[w][p*2][jj] = lgA[jj];
        red[w][p*2+1][jj] = lgB[jj];
      }
  }
  __syncthreads();
  if(tid == 0){
    float temp = log1pf(__expf(ltp[0]));
    #pragma unroll
    for(int hh=0;hh<4;hh++){
      float lo[4]; float mx = -1e30f;
      #pragma unroll
      for(int jj=0;jj<4;jj++){
        lo[jj] = (red[0][hh][jj]+red[1][hh][jj]+red[2][hh][jj]+red[3][hh][jj]
                  + b2[jj]) / temp;
        mx = fmaxf(mx, lo[jj]);
      }
      float e[4], se = 0.f;
      #pragma unroll
      for(int jj=0;jj<4;jj++){ e[jj] = __expf(lo[jj]-mx); se += e[jj]; }
      float s2 = 0.f;
      #pragma unroll
      for(int jj=0;jj<4;jj++){ e[jj] = fmaxf(e[jj]/se, 0.02f); s2 += e[jj]; }
      float inv = 1.f/s2;
      #pragma unroll
      for(int jj=0;jj<4;jj++) pl[hh][jj] = e[jj]*inv;
    }
  }
  __syncthreads();
  // combine + rmsnorm: thread tid owns dim d=tid for each of 4 heads
  float o4[4], ss4[4];
  #pragma unroll
  for(int h=0; h<4; h++){
    size_t ix = (bl*4 + h)*256 + tid;
    float rg = 1.f/(1.f + __expf(-crl[h]));
    float o = (pl[h][0] + rg)*bs2f(ls[ix]) + pl[h][1]*bs2f(ll[ix])
            + pl[h][2]*bs2f(dd[ix]) + pl[h][3]*bs2f(vv[ix]);
    o4[h] = o;
    ss4[h] = o*o;
  }
  #pragma unroll
  for(int off=32; off; off>>=1)
    #pragma unroll
    for(int h=0; h<4; h++) ss4[h] += __shfl_down(ss4[h], off);
  if(lane == 0)
    #pragma unroll
    for(int h=0; h<4; h++) rr2[w][h] = ss4[h];
  __syncthreads();
  float nwv = nw[tid];
  #pragma unroll
  for(int h=0; h<4; h++){
    float tot = rr2[0][h]+rr2[1][h]+rr2[2][h]+rr2[3][h];
    float rms = rsqrtf(tot*(1.f/256.f) + 1e-5f);
    size_t ix = (bl*4 + h)*256 + tid;
    obf[ix] = f2bs(o4[h]*rms*nwv);
  }
}

// ---------------- launch ----------------
extern "C" void kernel_launch(void* const* d_in, const int* in_sizes, int n_in,
                              void* d_out, int out_size, void* d_ws, size_t ws_size,
                              hipStream_t stream){
  const float* hs  = (const float*)d_in[0];
  const float* qw  = (const float*)d_in[1];
  const float* kw  = (const float*)d_in[2];
  const float* vw  = (const float*)d_in[3];
  const float* bw  = (const float*)d_in[4];
  const float* qcw = (const float*)d_in[5];
  const float* kcw = (const float*)d_in[6];
  const float* vcw = (const float*)d_in[7];
  const float* fsw = (const float*)d_in[8];
  const float* flw = (const float*)d_in[9];
  const float* w1  = (const float*)d_in[10];
  const float* b1  = (const float*)d_in[11];
  const float* w2  = (const float*)d_in[12];
  const float* b2  = (const float*)d_in[13];
  const float* ltp = (const float*)d_in[14];
  const float* crl = (const float*)d_in[15];
  const float* nw  = (const float*)d_in[16];
  const float* ow  = (const float*)d_in[17];

  char* ws = (char*)d_ws;
  size_t off = 0;
  auto alloc = [&](size_t bytes)->char*{
    char* pp = ws + off; off += (bytes + 255) & ~(size_t)255; return pp;
  };
  short* hs_bf  = (short*)alloc((size_t)NBL*1024*2);
  short* wmega  = (short*)alloc((size_t)4096*1024*2);   // packed qw|kw|vw|w1a
  short* ow_bf  = (short*)alloc((size_t)1024*1024*2);   // out-proj weight bf16
  short* qp_bf  = (short*)alloc((size_t)NBL*1024*2);    // q proj -> qn
  short* kp_bf  = (short*)alloc((size_t)NBL*1024*2);    // k proj -> wn -> o_bf
  short* vp_bf  = (short*)alloc((size_t)NBL*1024*2);    // v proj -> kT
  short* g_bf   = (short*)alloc((size_t)NBL*1024*2);    // gate hidden (lives to gatecomb)
  short* qc_bf  = (short*)alloc((size_t)NBL*1024*2);    // conv q -> ls
  short* kc_bf  = (short*)alloc((size_t)NBL*1024*2);    // conv k -> ll
  short* vc_bf  = (short*)alloc((size_t)NBL*1024*2);    // conv v (v_direct)
  float* u_f    = (float*)alloc((size_t)NBL*1024*4);
  short* do_bf  = (short*)alloc((size_t)NBL*1024*2);
  short* at_bf  = (short*)alloc((size_t)NB*NH*NCH*1024*2);
  float* beta   = (float*)alloc((size_t)NBL*4*4);
  if(ws_size < off) return;

  short* qn_bf = qp_bf; short* wn_bf = kp_bf; short* kT_bf = vp_bf;
  short* ls_bf = qc_bf; short* ll_bf = kc_bf;
  short* o_bf  = kp_bf;

  k_cast8<<<dim3(4096),dim3(256),0,stream>>>(hs, hs_bf, NBL*1024/8);
  k_castW<<<dim3(512,5),dim3(256),0,stream>>>(qw, kw, vw, w1, ow, wmega, ow_bf);
  // fused QKVG projection
  k_gemm4<<<dim3(64,32),dim3(256),0,stream>>>(hs_bf, wmega, qp_bf, kp_bf, vp_bf, g_bf);
  // short conv + silu (3-in-1)
  k_conv_silu3<<<dim3(4096,3),dim3(256),0,stream>>>(qp_bf, kp_bf, vp_bf,
                                                    qcw, kcw, vcw,
                                                    qc_bf, kc_bf, vc_bf);
  k_beta<<<dim3(2048),dim3(256),0,stream>>>(hs, bw, beta);
  // delta rule
  k_phaseA<<<dim3(1024),dim3(256),0,stream>>>(qc_bf, kc_bf, vc_bf, beta,
                                              qn_bf, wn_bf, kT_bf, at_bf, u_f);
  k_phaseB<<<dim3(128),dim3(256),0,stream>>>(qn_bf, wn_bf, kT_bf, at_bf, u_f, do_bf);
  // FIR convs
  k_fir<<<dim3(1024),dim3(256),0,stream>>>(vc_bf, fsw, flw, ls_bf, ll_bf);
  // fused gate MLP + combine + rmsnorm
  k_gatecomb<<<dim3(8192),dim3(256),0,stream>>>(ls_bf, ll_bf, do_bf, vc_bf, g_bf,
                                                w1, b1, w2, b2, ltp, crl, nw, o_bf);
  // output projection (weight pre-cast in k_castW)
  k_gemm<float><<<dim3(64,8),dim3(256),0,stream>>>(o_bf, ow_bf, (float*)d_out,
                                                   NBL, 1024, 1024);
}

// Round 17
// 556.942 us; speedup vs baseline: 1.0185x; 1.0185x over previous
//
#include <hip/hip_runtime.h>
#include <hip/hip_bf16.h>
#include <math.h>

// Sizes
#define NB 2
#define NL 4096
#define ND 1024
#define NH 4
#define NDK 256
#define NDV 256
#define NCH 128          // chunks per (b,h)
#define NBL (NB*NL)      // 8192

typedef __attribute__((ext_vector_type(8))) short short8;
typedef __attribute__((ext_vector_type(4))) short short4v;
typedef __attribute__((ext_vector_type(4))) float float4v;

#define MFMA16(a,b,c) __builtin_amdgcn_mfma_f32_16x16x32_bf16(a,b,c,0,0,0)

__device__ __forceinline__ short f2bs(float f){
  union { __hip_bfloat16 h; short s; } u; u.h = __float2bfloat16(f); return u.s;
}
__device__ __forceinline__ float bs2f(short s){
  union { float f; unsigned u; } u; u.u = ((unsigned)(unsigned short)s) << 16; return u.f;
}
__device__ __forceinline__ void store_c(float* p, float v){ *p = v; }
__device__ __forceinline__ void store_c(short* p, float v){ *p = f2bs(v); }

__device__ __forceinline__ void gload16(const short* g, short* l){
  __builtin_amdgcn_global_load_lds(
      (const __attribute__((address_space(1))) unsigned int*)g,
      (__attribute__((address_space(3))) unsigned int*)l, 16, 0, 0);
}
__device__ __forceinline__ void lds_barrier(){
  asm volatile("s_waitcnt lgkmcnt(0)" ::: "memory");
  __builtin_amdgcn_s_barrier();
  asm volatile("" ::: "memory");
}

// ---------------- casts (vectorized, G13) ----------------
__global__ void k_cast8(const float* __restrict__ s, short* __restrict__ d, int n8){
  int i = blockIdx.x*256 + threadIdx.x;
  if(i >= n8) return;
  const float4v a = *(const float4v*)(s + (size_t)i*8);
  const float4v b = *(const float4v*)(s + (size_t)i*8 + 4);
  short8 o;
  #pragma unroll
  for(int j=0;j<4;j++){ o[j] = f2bs(a[j]); o[4+j] = f2bs(b[j]); }
  *(short8*)(d + (size_t)i*8) = o;
}
// merged weight cast: y=0..2 -> qw/kw/vw -> wmega; y=3 -> w1 cols 0..1023 -> wmega;
// y=4 -> ow -> owbf
__global__ void k_castW(const float* __restrict__ qw, const float* __restrict__ kw,
                        const float* __restrict__ vw, const float* __restrict__ w1,
                        const float* __restrict__ ow, short* __restrict__ wmega,
                        short* __restrict__ owbf){
  const int which = blockIdx.y;
  const int i = blockIdx.x*256 + threadIdx.x;   // 131072 groups of 8
  short* d;
  const float* sp;
  size_t doff;
  if(which < 3){
    const float* s = which==0 ? qw : which==1 ? kw : vw;
    d = wmega + (size_t)which*1024*1024;
    sp = s + (size_t)i*8;
    doff = (size_t)i*8;
  } else if(which == 3){
    int r = i >> 7, c0 = (i & 127)*8;
    d = wmega + (size_t)3*1024*1024;
    sp = w1 + (size_t)r*1040 + c0;
    doff = (size_t)r*1024 + c0;
  } else {
    d = owbf;
    sp = ow + (size_t)i*8;
    doff = (size_t)i*8;
  }
  const float4v a = *(const float4v*)sp;
  const float4v b = *(const float4v*)(sp + 4);
  short8 o;
  #pragma unroll
  for(int j=0;j<4;j++){ o[j] = f2bs(a[j]); o[4+j] = f2bs(b[j]); }
  *(short8*)(d + doff) = o;
}

// ---------------- fused QKVG GEMM: C(8192x4096) = A*Wmega^T, 4-way output ----
__launch_bounds__(256)
__global__ void k_gemm4(const short* __restrict__ A, const short* __restrict__ Bt,
                        short* __restrict__ oq, short* __restrict__ ok,
                        short* __restrict__ ov, short* __restrict__ og){
  const int K = 1024;
  __shared__ short As[128*32];
  __shared__ short Bs[128*32];
  const int tid = threadIdx.x;
  const int w = tid >> 6, lane = tid & 63, lr = lane & 15, lg = lane >> 4;
  const int bm = blockIdx.x*128 + (w >> 1)*64;
  const int bnl = (blockIdx.y & 7)*128 + (w & 1)*64;   // col within 1024-wide output
  short* C = (blockIdx.y>>3)==0 ? oq : (blockIdx.y>>3)==1 ? ok
           : (blockIdx.y>>3)==2 ? ov : og;
  float4v acc[4][4];
  #pragma unroll
  for(int i=0;i<4;i++)
    #pragma unroll
    for(int j=0;j<4;j++) acc[i][j] = (float4v){0.f,0.f,0.f,0.f};
  const short* ga0 = A  + (size_t)(blockIdx.x*128 + (tid>>2))*K + (tid&3)*8;
  const short* ga1 = ga0 + (size_t)64*K;
  const short* gb0 = Bt + (size_t)(blockIdx.y*128 + (tid>>2))*K + (tid&3)*8;
  const short* gb1 = gb0 + (size_t)64*K;
  short* la0 = As + w*512;
  short* la1 = As + 2048 + w*512;
  short* lb0 = Bs + w*512;
  short* lb1 = Bs + 2048 + w*512;
  const int arow = (w>>1)*64, brow = (w&1)*64;
  for(int kk=0; kk<K; kk+=32){
    gload16(ga0+kk, la0);
    gload16(ga1+kk, la1);
    gload16(gb0+kk, lb0);
    gload16(gb1+kk, lb1);
    __syncthreads();
    short8 a[4], b[4];
    #pragma unroll
    for(int i=0;i<4;i++) a[i] = *(const short8*)(As + (arow + i*16 + lr)*32 + lg*8);
    #pragma unroll
    for(int j=0;j<4;j++) b[j] = *(const short8*)(Bs + (brow + j*16 + lr)*32 + lg*8);
    #pragma unroll
    for(int i=0;i<4;i++)
      #pragma unroll
      for(int j=0;j<4;j++)
        acc[i][j] = MFMA16(a[i], b[j], acc[i][j]);
    __syncthreads();
  }
  #pragma unroll
  for(int i=0;i<4;i++){
    int row0 = bm + i*16 + lg*4;
    #pragma unroll
    for(int j=0;j<4;j++){
      short* cp = C + (size_t)row0*1024 + bnl + j*16 + lr;
      #pragma unroll
      for(int r=0;r<4;r++) cp[(size_t)r*1024] = f2bs(acc[i][j][r]);
    }
  }
}

// ---------------- GEMM: C(MxN) = A(MxK)*Bt(NxK)^T, m97 structure ------------
template<typename OT>
__launch_bounds__(256)
__global__ void k_gemm(const short* __restrict__ A, const short* __restrict__ Bt,
                       OT* __restrict__ C, int M, int N, int K){
  __shared__ short As[128*32];
  __shared__ short Bs[128*32];
  const int tid = threadIdx.x;
  const int w = tid >> 6, lane = tid & 63, lr = lane & 15, lg = lane >> 4;
  const int bm = blockIdx.x*128 + (w >> 1)*64;
  const int bn = blockIdx.y*128 + (w & 1)*64;
  float4v acc[4][4];
  #pragma unroll
  for(int i=0;i<4;i++)
    #pragma unroll
    for(int j=0;j<4;j++) acc[i][j] = (float4v){0.f,0.f,0.f,0.f};
  const short* ga0 = A  + (size_t)(blockIdx.x*128 + (tid>>2))*K + (tid&3)*8;
  const short* ga1 = ga0 + (size_t)64*K;
  const short* gb0 = Bt + (size_t)(blockIdx.y*128 + (tid>>2))*K + (tid&3)*8;
  const short* gb1 = gb0 + (size_t)64*K;
  short* la0 = As + w*512;
  short* la1 = As + 2048 + w*512;
  short* lb0 = Bs + w*512;
  short* lb1 = Bs + 2048 + w*512;
  const int arow = (w>>1)*64, brow = (w&1)*64;
  for(int kk=0; kk<K; kk+=32){
    gload16(ga0+kk, la0);
    gload16(ga1+kk, la1);
    gload16(gb0+kk, lb0);
    gload16(gb1+kk, lb1);
    __syncthreads();
    short8 a[4], b[4];
    #pragma unroll
    for(int i=0;i<4;i++) a[i] = *(const short8*)(As + (arow + i*16 + lr)*32 + lg*8);
    #pragma unroll
    for(int j=0;j<4;j++) b[j] = *(const short8*)(Bs + (brow + j*16 + lr)*32 + lg*8);
    #pragma unroll
    for(int i=0;i<4;i++)
      #pragma unroll
      for(int j=0;j<4;j++)
        acc[i][j] = MFMA16(a[i], b[j], acc[i][j]);
    __syncthreads();
  }
  #pragma unroll
  for(int i=0;i<4;i++){
    int row0 = bm + i*16 + lg*4;
    #pragma unroll
    for(int j=0;j<4;j++){
      OT* cp = C + (size_t)row0*N + bn + j*16 + lr;
      #pragma unroll
      for(int r=0;r<4;r++) store_c(cp + (size_t)r*N, acc[i][j][r]);
    }
  }
}

// ---------------- depthwise causal conv K=4 + SiLU (merged 3-in-1) ----------
__global__ void k_conv_silu3(const short* __restrict__ qp, const short* __restrict__ kp,
                             const short* __restrict__ vp, const float* __restrict__ qcw,
                             const float* __restrict__ kcw, const float* __restrict__ vcw,
                             short* __restrict__ qc, short* __restrict__ kc,
                             short* __restrict__ vc){
  const int which = blockIdx.y;
  const short* x = which==0 ? qp : which==1 ? kp : vp;
  const float* wgt = which==0 ? qcw : which==1 ? kcw : vcw;
  short* y = which==0 ? qc : which==1 ? kc : vc;
  int i8 = blockIdx.x*256 + threadIdx.x;
  int c0 = (i8 & 127)*8;
  int l = (i8 >> 7) & (NL-1);
  size_t base = (size_t)i8*8;
  short8 xv[4];
  #pragma unroll
  for(int t=0;t<4;t++)
    xv[t] = (l >= t) ? *(const short8*)(x + base - (size_t)t*1024)
                     : (short8){0,0,0,0,0,0,0,0};
  short8 o;
  #pragma unroll
  for(int j=0;j<8;j++){
    const float4v w4 = *(const float4v*)(wgt + (c0+j)*4);
    float acc = 0.f;
    #pragma unroll
    for(int t=0;t<4;t++) if(l >= t) acc += bs2f(xv[t][j]) * w4[3-t];
    o[j] = f2bs(acc / (1.f + __expf(-acc)));
  }
  *(short8*)(y + base) = o;
}

// ---------------- beta = max(sigmoid(hs @ bw^T), 1e-6) ----------------
__global__ void k_beta(const float* __restrict__ hs, const float* __restrict__ bw,
                       float* __restrict__ beta){
  int w = threadIdx.x >> 6, lane = threadIdx.x & 63;
  int bl = blockIdx.x*4 + w;
  const float* x = hs + (size_t)bl*1024;
  float a[4] = {0.f,0.f,0.f,0.f};
  for(int d=lane; d<1024; d+=64){
    float xv = x[d];
    #pragma unroll
    for(int hh=0;hh<4;hh++) a[hh] += xv * bw[hh*1024 + d];
  }
  #pragma unroll
  for(int off=32; off; off>>=1)
    #pragma unroll
    for(int hh=0;hh<4;hh++) a[hh] += __shfl_down(a[hh], off);
  if(lane == 0)
    #pragma unroll
    for(int hh=0;hh<4;hh++)
      beta[(size_t)bl*4 + hh] = fmaxf(1.f/(1.f+__expf(-a[hh])), 1e-6f);
}

// ---------------- delta phase A: per-chunk prep (reg substitution) ----------
#define PADA 260
__launch_bounds__(256)
__global__ void k_phaseA(const short* __restrict__ q, const short* __restrict__ k,
                         const short* __restrict__ v, const float* __restrict__ beta,
                         short* __restrict__ qn_o, short* __restrict__ wn_o,
                         short* __restrict__ kT_o, short* __restrict__ at_o,
                         float* __restrict__ u_o){
  __shared__ float qn[32*PADA];
  __shared__ float kn[32*PADA];
  __shared__ float vb[32*PADA];
  __shared__ float kb[32*PADA];
  __shared__ float Ml[32*33];
  __shared__ float bet[32];
  const int tid = threadIdx.x;
  const int n = blockIdx.x % NCH;
  const int h = (blockIdx.x / NCH) % NH;
  const int b = blockIdx.x / (NCH*NH);
  size_t rowbase = ((size_t)b*NL + n*32)*1024 + h*256;
  if(tid < 32) bet[tid] = beta[((size_t)b*NL + n*32 + tid)*4 + h];
  for(int r=0;r<32;r++){
    qn[r*PADA + tid] = bs2f(q[rowbase + (size_t)r*1024 + tid]);
    kn[r*PADA + tid] = bs2f(k[rowbase + (size_t)r*1024 + tid]);
    vb[r*PADA + tid] = bs2f(v[rowbase + (size_t)r*1024 + tid]);
  }
  __syncthreads();
  { // l2norm q,k rows; kb = kn*beta; vb *= beta
    int row = tid >> 3, sub = tid & 7;
    float sq = 0.f, sk = 0.f;
    for(int kk=0; kk<32; kk++){
      int d = sub + 8*kk;
      float a0 = qn[row*PADA+d]; sq += a0*a0;
      float a1 = kn[row*PADA+d]; sk += a1*a1;
    }
    #pragma unroll
    for(int off=1; off<8; off<<=1){ sq += __shfl_xor(sq, off); sk += __shfl_xor(sk, off); }
    float rq = rsqrtf(sq + 1e-6f), rk = rsqrtf(sk + 1e-6f);
    float be = bet[row];
    for(int kk=0; kk<32; kk++){
      int d = sub + 8*kk;
      qn[row*PADA+d] *= rq;
      float kv = kn[row*PADA+d]*rk;
      kn[row*PADA+d] = kv;
      kb[row*PADA+d] = kv*be;
      vb[row*PADA+d] *= be;
    }
  }
  __syncthreads();
  { // MFMA: w0-1: M = kb@kn^T (strict lower) -> Ml; w2-3: attn = tril(qn@kn^T)
    int w = tid >> 6, lane = tid & 63, lr = lane & 15, lg = lane >> 4;
    int m0 = (w & 1)*16;
    const float* Asrc = (w < 2) ? kb : qn;
    float4v acc0 = (float4v){0.f,0.f,0.f,0.f}, acc1 = (float4v){0.f,0.f,0.f,0.f};
    for(int kc=0; kc<8; kc++){
      int kof = kc*32 + lg*8;
      short8 af, b0, b1;
      const float* ap  = Asrc + (m0+lr)*PADA + kof;
      const float* bp0 = kn + lr*PADA + kof;
      const float* bp1 = kn + (16+lr)*PADA + kof;
      #pragma unroll
      for(int j=0;j<8;j++){ af[j]=f2bs(ap[j]); b0[j]=f2bs(bp0[j]); b1[j]=f2bs(bp1[j]); }
      acc0 = MFMA16(af, b0, acc0);
      acc1 = MFMA16(af, b1, acc1);
    }
    if(w < 2){
      #pragma unroll
      for(int r=0;r<4;r++){
        int row = m0 + lg*4 + r;
        Ml[row*33 + lr]      = (lr      < row) ? acc0[r] : 0.f;
        Ml[row*33 + 16 + lr] = ((16+lr) < row) ? acc1[r] : 0.f;
      }
    } else {
      size_t abase = (size_t)blockIdx.x * 1024;
      #pragma unroll
      for(int r=0;r<4;r++){
        int row = m0 + lg*4 + r;
        at_o[abase + row*32 + lr]      = (lr      <= row) ? f2bs(acc0[r]) : (short)0;
        at_o[abase + row*32 + 16 + lr] = ((16+lr) <= row) ? f2bs(acc1[r]) : (short)0;
      }
    }
  }
  __syncthreads();
  // forward substitution in REGISTERS: thread tid owns column d=tid of vb,kb.
  float vbr[32], kbr[32];
  #pragma unroll
  for(int t=0;t<32;t++){
    vbr[t] = vb[t*PADA + tid];
    kbr[t] = kb[t*PADA + tid];
  }
  #pragma unroll
  for(int i=1;i<32;i++){
    float su = 0.f, sw = 0.f;
    const float* Mr = Ml + i*33;
    #pragma unroll
    for(int t=0;t<i;t++){
      float m = Mr[t];
      su += m * vbr[t];
      sw += m * kbr[t];
    }
    vbr[i] -= su;
    kbr[i] -= sw;
  }
  { // stores: wn/u straight from registers; qn/kT from LDS
    size_t obase = (size_t)blockIdx.x * 8192;
    #pragma unroll
    for(int it=0; it<32; it++){
      int idx = it*256 + tid;
      qn_o[obase + idx] = f2bs(qn[it*PADA + tid]);
      wn_o[obase + idx] = f2bs(-kbr[it]);
      u_o [obase + idx] = vbr[it];
      int tt = idx & 31, dd = idx >> 5;
      kT_o[obase + idx] = f2bs(kn[tt*PADA + dd]);
    }
  }
}

// ---------------- delta phase B: R8 4-wave structure (proven 182us) ----------
struct FragsB {
  short8 a[8];     // wn (w<2) or qn (w>=2) fragments
  short8 kt[4];    // kT fragments
  short8 at;       // attn fragment (w>=2 only)
  float4v u;       // u slice (w<2 only)
};

__device__ __forceinline__ void loadFrags(FragsB& f, size_t cb,
    const short* __restrict__ qn, const short* __restrict__ wn,
    const short* __restrict__ kT, const short* __restrict__ at,
    const float* __restrict__ u, int w, int lr, int lg, int m0, int c0){
  const short* kT_b = kT + cb*8192;
  #pragma unroll
  for(int mi=0;mi<4;mi++)
    f.kt[mi] = *(const short8*)(kT_b + ((w*4+mi)*16 + lr)*32 + lg*8);
  if(w < 2){
    const short* wn_b = wn + cb*8192;
    #pragma unroll
    for(int kc=0;kc<8;kc++)
      f.a[kc] = *(const short8*)(wn_b + (m0+lr)*256 + kc*32 + lg*8);
    const float* up = u + cb*8192 + (size_t)(m0 + lg*4)*256 + c0 + lr;
    #pragma unroll
    for(int r=0;r<4;r++) f.u[r] = up[(size_t)r*256];
  } else {
    const short* qn_b = qn + cb*8192;
    #pragma unroll
    for(int kc=0;kc<8;kc++)
      f.a[kc] = *(const short8*)(qn_b + (m0+lr)*256 + kc*32 + lg*8);
    f.at = *(const short8*)(at + cb*1024 + (m0+lr)*32 + lg*8);
  }
}

__device__ __forceinline__ void computeChunk(const FragsB& f, int n,
    float4v (&Sreg)[4], float* __restrict__ ua, short* __restrict__ ScT,
    short* __restrict__ dout, int b, int h, int c0,
    int w, int lr, int lg, int m0, int swz){
  char* scb = (char*)ScT;
  lds_barrier();   // prev chunk's ScT writes visible
  float4v oacc = (float4v){0.f,0.f,0.f,0.f};
  if(w < 2){
    float4v acc = f.u, acc2 = (float4v){0.f,0.f,0.f,0.f};
    #pragma unroll
    for(int kc=0;kc<4;kc++){
      short8 s0 = *(const short8*)(scb + (((lr<<9) + ((kc*32 + lg*8)<<1)) ^ swz));
      short8 s1 = *(const short8*)(scb + (((lr<<9) + (((kc+4)*32 + lg*8)<<1)) ^ swz));
      acc  = MFMA16(f.a[kc],   s0, acc);
      acc2 = MFMA16(f.a[kc+4], s1, acc2);
    }
    #pragma unroll
    for(int r=0;r<4;r++) ua[(m0 + lg*4 + r)*18 + lr] = acc[r] + acc2[r];
  } else {
    float4v acc2 = (float4v){0.f,0.f,0.f,0.f};
    #pragma unroll
    for(int kc=0;kc<4;kc++){
      short8 s0 = *(const short8*)(scb + (((lr<<9) + ((kc*32 + lg*8)<<1)) ^ swz));
      short8 s1 = *(const short8*)(scb + (((lr<<9) + (((kc+4)*32 + lg*8)<<1)) ^ swz));
      oacc = MFMA16(f.a[kc],   s0, oacc);
      acc2 = MFMA16(f.a[kc+4], s1, acc2);
    }
    #pragma unroll
    for(int r=0;r<4;r++) oacc[r] += acc2[r];
  }
  lds_barrier();   // ua visible
  short8 bu;
  #pragma unroll
  for(int j=0;j<8;j++) bu[j] = f2bs(ua[(lg*8 + j)*18 + lr]);
  if(w >= 2){
    oacc = MFMA16(f.at, bu, oacc);
    short* ob = dout + ((size_t)b*NL + n*32 + m0 + lg*4)*1024 + h*256 + c0 + lr;
    #pragma unroll
    for(int r=0;r<4;r++) ob[(size_t)r*1024] = f2bs(oacc[r]);
  }
  #pragma unroll
  for(int mi=0; mi<4; mi++){
    Sreg[mi] = MFMA16(f.kt[mi], bu, Sreg[mi]);   // S += kT @ u_adj
    int rowb = (w*4 + mi)*16 + lg*4;
    short4v pk;
    #pragma unroll
    for(int r=0;r<4;r++) pk[r] = f2bs(Sreg[mi][r]);
    *(short4v*)(scb + (((lr<<9) + (rowb<<1)) ^ swz)) = pk;
  }
}

// grid 128: chain = bid&7 (all 16 blocks of a chain -> same XCD L2), cblk = bid>>3
__launch_bounds__(256, 1)
__global__ void k_phaseB(const short* __restrict__ qn, const short* __restrict__ wn,
                         const short* __restrict__ kT, const short* __restrict__ at,
                         const float* __restrict__ u, short* __restrict__ dout){
  __shared__ float ua[32*18];    // u_adj handoff
  __shared__ short ScT[4096];    // bf16 S shadow, col-major [c][row], XOR-swizzled
  const int tid = threadIdx.x;
  const int chain = blockIdx.x & 7;
  const int cblk = blockIdx.x >> 3;
  const int b = chain >> 2, h = chain & 3;
  const int c0 = cblk * 16;
  for(int i=tid; i<4096; i+=256) ScT[i] = 0;
  const int w = tid >> 6, lane = tid & 63, lr = lane & 15, lg = lane >> 4;
  const int m0 = (w & 1)*16;
  const size_t chunkbase = (size_t)(b*NH + h) * NCH;
  const int swz = (lr & 7) << 4;
  float4v Sreg[4];
  #pragma unroll
  for(int mi=0;mi<4;mi++) Sreg[mi] = (float4v){0.f,0.f,0.f,0.f};
  __syncthreads();
  FragsB fA, fB;
  loadFrags(fA, chunkbase, qn, wn, kT, at, u, w, lr, lg, m0, c0);
  for(int n=0; n<NCH; n+=2){
    loadFrags(fB, chunkbase + n+1, qn, wn, kT, at, u, w, lr, lg, m0, c0);
    computeChunk(fA, n, Sreg, ua, ScT, dout, b, h, c0, w, lr, lg, m0, swz);
    if(n+2 < NCH)
      loadFrags(fA, chunkbase + n+2, qn, wn, kT, at, u, w, lr, lg, m0, c0);
    computeChunk(fB, n+1, Sreg, ua, ScT, dout, b, h, c0, w, lr, lg, m0, swz);
  }
}

// ---------------- FIR convs (K=5 and K=64): register sliding window, no LDS --
__launch_bounds__(256, 2)
__global__ void k_fir(const short* __restrict__ v, const float* __restrict__ wS,
                      const float* __restrict__ wL, short* __restrict__ ls,
                      short* __restrict__ ll){
  const int tid = threadIdx.x;                 // d within head
  const int lt = blockIdx.x % (NL/32);
  const int h = (blockIdx.x / (NL/32)) % NH;
  const int b = blockIdx.x / ((NL/32)*NH);
  const int l0 = lt*32;
  const size_t colbase = (size_t)b*NL*1024 + h*256 + tid;
  const float* wLp = wL + (size_t)h*16384 + tid*64;
  const float* wSp = wS + (size_t)h*1280 + tid*5;
  float accL[32], accS[32];
  #pragma unroll
  for(int i=0;i<32;i++){ accL[i]=0.f; accS[i]=0.f; }
  { // chunk 0: taps j=0..31
    float w[32];
    #pragma unroll
    for(int j=0;j<32;j++) w[j] = wLp[j];
    float val[63];
    #pragma unroll
    for(int s=0;s<63;s++){
      int l = l0 - 63 + s;
      int lc = l < 0 ? 0 : l;
      float x = bs2f(v[colbase + (size_t)lc*1024]);
      val[s] = l < 0 ? 0.f : x;
    }
    #pragma unroll
    for(int i=0;i<32;i++)
      #pragma unroll
      for(int j=0;j<32;j++)
        accL[i] += val[i+j]*w[j];
  }
  { // chunk 1: taps j=32..63 (+ accS)
    float w[32];
    #pragma unroll
    for(int j=0;j<32;j++) w[j] = wLp[32+j];
    float w5[5];
    #pragma unroll
    for(int j=0;j<5;j++) w5[j] = wSp[j];
    float val[63];
    #pragma unroll
    for(int s=0;s<63;s++){
      int l = l0 - 31 + s;
      int lc = l < 0 ? 0 : l;
      float x = bs2f(v[colbase + (size_t)lc*1024]);
      val[s] = l < 0 ? 0.f : x;
    }
    #pragma unroll
    for(int i=0;i<32;i++){
      #pragma unroll
      for(int j=0;j<32;j++)
        accL[i] += val[i+j]*w[j];
      #pragma unroll
      for(int j=0;j<5;j++)
        accS[i] += val[i+27+j]*w5[j];  // v[l0-31+i+27+j] = v[l-4+j]
    }
  }
  #pragma unroll
  for(int i=0;i<32;i++){
    size_t ox = colbase + (size_t)(l0+i)*1024;
    ll[ox] = f2bs(accL[i]);
    ls[ox] = f2bs(accS[i]);
  }
}

// ---------------- fused gate + combine + rmsnorm (R15 version) ---------------
__launch_bounds__(256)
__global__ void k_gatecomb(const short* __restrict__ ls, const short* __restrict__ ll,
                           const short* __restrict__ dd, const short* __restrict__ vv,
                           const short* __restrict__ G, const float* __restrict__ w1,
                           const float* __restrict__ b1, const float* __restrict__ w2,
                           const float* __restrict__ b2, const float* __restrict__ ltp,
                           const float* __restrict__ crl, const float* __restrict__ nw,
                           short* __restrict__ obf){
  __shared__ float st[4][16];
  __shared__ float red[4][4];
  __shared__ float pl[4][4];
  __shared__ float rr2[4][4];
  const int tid = threadIdx.x;
  const size_t bl = blockIdx.x;
  {
    int row = tid >> 4, ln = tid & 15;
    int ten = row >> 2, hh = row & 3;
    const short* base = (ten==0 ? ls : ten==1 ? ll : ten==2 ? dd : vv) + (bl*4 + hh)*256;
    float s1=0.f, s2=0.f, sa=0.f;
    for(int kk=0; kk<16; kk++){
      float x = bs2f(base[ln + 16*kk]);
      s1 += x; s2 += x*x; sa += fabsf(x);
    }
    #pragma unroll
    for(int off=1; off<16; off<<=1){
      s1 += __shfl_xor(s1, off); s2 += __shfl_xor(s2, off); sa += __shfl_xor(sa, off);
    }
    if(ln == 0){
      float mean = s1 * (1.f/256.f);
      st[hh][ten*4+0] = mean;
      st[hh][ten*4+1] = s2*(1.f/256.f) - mean*mean;
      st[hh][ten*4+2] = sa*(1.f/256.f);
      st[hh][ten*4+3] = sqrtf(s2);
    }
  }
  __syncthreads();
  const int w = tid >> 6, lane = tid & 63;
  float temp = log1pf(__expf(ltp[0]));
  for(int hh=0; hh<4; hh++){
    float sreg[16];
    #pragma unroll
    for(int s=0;s<16;s++) sreg[s] = st[hh][s];
    float lg4[4] = {0.f,0.f,0.f,0.f};
    for(int ii=0; ii<4; ii++){
      int i = tid + ii*256;
      float g = bs2f(G[bl*1024 + i]) + b1[i];
      const float* wr = w1 + (size_t)i*1040 + 1024;
      #pragma unroll
      for(int s=0;s<16;s++) g += sreg[s]*wr[s];
      float z = 1.5957691216057308f*(g + 0.044715f*g*g*g);
      float hg = g / (1.f + __expf(-z));
      #pragma unroll
      for(int jj=0;jj<4;jj++) lg4[jj] += hg * w2[jj*1024 + i];
    }
    #pragma unroll
    for(int off=32; off; off>>=1)
      #pragma unroll
      for(int jj=0;jj<4;jj++) lg4[jj] += __shfl_down(lg4[jj], off);
    if(lane == 0)
      #pragma unroll
      for(int jj=0;jj<4;jj++) red[w][jj] = lg4[jj];
    __syncthreads();
    if(tid == 0){
      float lo[4]; float mx = -1e30f;
      #pragma unroll
      for(int jj=0;jj<4;jj++){
        lo[jj] = (red[0][jj]+red[1][jj]+red[2][jj]+red[3][jj] + b2[jj]) / temp;
        mx = fmaxf(mx, lo[jj]);
      }
      float e[4], se = 0.f;
      #pragma unroll
      for(int jj=0;jj<4;jj++){ e[jj] = __expf(lo[jj]-mx); se += e[jj]; }
      float s2 = 0.f;
      #pragma unroll
      for(int jj=0;jj<4;jj++){ e[jj] = fmaxf(e[jj]/se, 0.02f); s2 += e[jj]; }
      float inv = 1.f/s2;
      #pragma unroll
      for(int jj=0;jj<4;jj++) pl[hh][jj] = e[jj]*inv;
    }
    __syncthreads();
  }
  // combine + rmsnorm: thread tid owns dim d=tid for each of 4 heads
  float o4[4], ss4[4];
  #pragma unroll
  for(int h=0; h<4; h++){
    size_t ix = (bl*4 + h)*256 + tid;
    float rg = 1.f/(1.f + __expf(-crl[h]));
    float o = (pl[h][0] + rg)*bs2f(ls[ix]) + pl[h][1]*bs2f(ll[ix])
            + pl[h][2]*bs2f(dd[ix]) + pl[h][3]*bs2f(vv[ix]);
    o4[h] = o;
    ss4[h] = o*o;
  }
  #pragma unroll
  for(int off=32; off; off>>=1)
    #pragma unroll
    for(int h=0; h<4; h++) ss4[h] += __shfl_down(ss4[h], off);
  if(lane == 0)
    #pragma unroll
    for(int h=0; h<4; h++) rr2[w][h] = ss4[h];
  __syncthreads();
  float nwv = nw[tid];
  #pragma unroll
  for(int h=0; h<4; h++){
    float tot = rr2[0][h]+rr2[1][h]+rr2[2][h]+rr2[3][h];
    float rms = rsqrtf(tot*(1.f/256.f) + 1e-5f);
    size_t ix = (bl*4 + h)*256 + tid;
    obf[ix] = f2bs(o4[h]*rms*nwv);
  }
}

// ---------------- launch ----------------
extern "C" void kernel_launch(void* const* d_in, const int* in_sizes, int n_in,
                              void* d_out, int out_size, void* d_ws, size_t ws_size,
                              hipStream_t stream){
  const float* hs  = (const float*)d_in[0];
  const float* qw  = (const float*)d_in[1];
  const float* kw  = (const float*)d_in[2];
  const float* vw  = (const float*)d_in[3];
  const float* bw  = (const float*)d_in[4];
  const float* qcw = (const float*)d_in[5];
  const float* kcw = (const float*)d_in[6];
  const float* vcw = (const float*)d_in[7];
  const float* fsw = (const float*)d_in[8];
  const float* flw = (const float*)d_in[9];
  const float* w1  = (const float*)d_in[10];
  const float* b1  = (const float*)d_in[11];
  const float* w2  = (const float*)d_in[12];
  const float* b2  = (const float*)d_in[13];
  const float* ltp = (const float*)d_in[14];
  const float* crl = (const float*)d_in[15];
  const float* nw  = (const float*)d_in[16];
  const float* ow  = (const float*)d_in[17];

  char* ws = (char*)d_ws;
  size_t off = 0;
  auto alloc = [&](size_t bytes)->char*{
    char* pp = ws + off; off += (bytes + 255) & ~(size_t)255; return pp;
  };
  short* hs_bf  = (short*)alloc((size_t)NBL*1024*2);
  short* wmega  = (short*)alloc((size_t)4096*1024*2);   // packed qw|kw|vw|w1a
  short* ow_bf  = (short*)alloc((size_t)1024*1024*2);   // out-proj weight bf16
  short* qp_bf  = (short*)alloc((size_t)NBL*1024*2);    // q proj -> qn
  short* kp_bf  = (short*)alloc((size_t)NBL*1024*2);    // k proj -> wn -> o_bf
  short* vp_bf  = (short*)alloc((size_t)NBL*1024*2);    // v proj -> kT
  short* g_bf   = (short*)alloc((size_t)NBL*1024*2);    // gate hidden (lives to gatecomb)
  short* qc_bf  = (short*)alloc((size_t)NBL*1024*2);    // conv q -> ls
  short* kc_bf  = (short*)alloc((size_t)NBL*1024*2);    // conv k -> ll
  short* vc_bf  = (short*)alloc((size_t)NBL*1024*2);    // conv v (v_direct)
  float* u_f    = (float*)alloc((size_t)NBL*1024*4);
  short* do_bf  = (short*)alloc((size_t)NBL*1024*2);
  short* at_bf  = (short*)alloc((size_t)NB*NH*NCH*1024*2);
  float* beta   = (float*)alloc((size_t)NBL*4*4);
  if(ws_size < off) return;

  short* qn_bf = qp_bf; short* wn_bf = kp_bf; short* kT_bf = vp_bf;
  short* ls_bf = qc_bf; short* ll_bf = kc_bf;
  short* o_bf  = kp_bf;

  k_cast8<<<dim3(4096),dim3(256),0,stream>>>(hs, hs_bf, NBL*1024/8);
  k_castW<<<dim3(512,5),dim3(256),0,stream>>>(qw, kw, vw, w1, ow, wmega, ow_bf);
  // fused QKVG projection
  k_gemm4<<<dim3(64,32),dim3(256),0,stream>>>(hs_bf, wmega, qp_bf, kp_bf, vp_bf, g_bf);
  // short conv + silu (3-in-1)
  k_conv_silu3<<<dim3(4096,3),dim3(256),0,stream>>>(qp_bf, kp_bf, vp_bf,
                                                    qcw, kcw, vcw,
                                                    qc_bf, kc_bf, vc_bf);
  k_beta<<<dim3(2048),dim3(256),0,stream>>>(hs, bw, beta);
  // delta rule
  k_phaseA<<<dim3(1024),dim3(256),0,stream>>>(qc_bf, kc_bf, vc_bf, beta,
                                              qn_bf, wn_bf, kT_bf, at_bf, u_f);
  k_phaseB<<<dim3(128),dim3(256),0,stream>>>(qn_bf, wn_bf, kT_bf, at_bf, u_f, do_bf);
  // FIR convs
  k_fir<<<dim3(1024),dim3(256),0,stream>>>(vc_bf, fsw, flw, ls_bf, ll_bf);
  // fused gate MLP + combine + rmsnorm
  k_gatecomb<<<dim3(8192),dim3(256),0,stream>>>(ls_bf, ll_bf, do_bf, vc_bf, g_bf,
                                                w1, b1, w2, b2, ltp, crl, nw, o_bf);
  // output projection (weight pre-cast in k_castW)
  k_gemm<float><<<dim3(64,8),dim3(256),0,stream>>>(o_bf, ow_bf, (float*)d_out,
                                                   NBL, 1024, 1024);
}